// Round 2
// baseline (616.275 us; speedup 1.0000x reference)
//
#include <hip/hip_runtime.h>
#include <math.h>

#define BB 4
#define TT 4
#define CC 256
#define HH 30
#define WW 40
#define HWS (HH*WW)          // 1200
#define CHW (CC*HWS)         // 307200
#define CHW4 (CHW/4)
#define PL 170               // LDS plane stride in pixels (168 + 2 pad, bank de-phase)

typedef __attribute__((ext_vector_type(8))) _Float16 half8;
typedef __attribute__((ext_vector_type(4))) float f32x4;

// ---------------------------------------------------------------------------
// h0 = sum_t x[b,t,:,:,:]; c0 = h0   (float4 vectorized)
// ---------------------------------------------------------------------------
__global__ void init_hc(const float* __restrict__ x,
                        float* __restrict__ h, float* __restrict__ c) {
    int id = blockIdx.x * 256 + threadIdx.x;
    if (id >= BB * CHW4) return;
    int b = id / CHW4;
    int rem = id - b * CHW4;
    const f32x4* xv = (const f32x4*)x;
    f32x4 s = {0.f, 0.f, 0.f, 0.f};
#pragma unroll
    for (int t = 0; t < TT; ++t)
        s += xv[((size_t)b * TT + t) * CHW4 + rem];
    ((f32x4*)h)[id] = s;
    ((f32x4*)c)[id] = s;
}

// ---------------------------------------------------------------------------
// Pack weights to f16: layout [kg=k/8][Cout][k%8]
// k = (src? 2304:0) + tap*256 + ci  over K=4608
// ---------------------------------------------------------------------------
__global__ void pack_weights(const float* __restrict__ W1,
                             const float* __restrict__ W2,
                             _Float16* __restrict__ wt, int Cout) {
    int idx = blockIdx.x * 256 + threadIdx.x;
    if (idx >= 4608 * Cout) return;
    int k = idx / Cout;
    int n = idx - k * Cout;
    float v = (k < 2304) ? W1[(size_t)k * Cout + n]
                         : W2[(size_t)(k - 2304) * Cout + n];
    wt[((size_t)(k >> 3) * Cout + n) * 8 + (k & 7)] = (_Float16)v;
}

// ---------------------------------------------------------------------------
// MFMA dual 3x3 conv, f16.
// Work decomposition: 16 slices (y = n-chunk 0..NY-1, z = 0..ZT-1 where
// z -> (src, ci-chunk)); 60 M-tiles per slice (4 batches x 15 two-row tiles).
// XCD-aware flat grid: linear block id -> XCD = id&7 (HW round-robin);
// XCD i owns slices {2i, 2i+1} with slice = z*NY + y (same-z pairing, so the
// pair shares its activation source too). Per-XCD weight working set becomes
// 2 slices (gate: 1.18 MB, att: 295 KB) -> L2-resident, instead of all 16
// slices (9.4 MB) thrashing per-XCD L2 and bouncing off Infinity Cache.
// Pipelined schedule: double-buffered LDS act tile, one barrier per K-iter,
// stage loads issued one iter ahead, rolling weight register prefetch.
// ---------------------------------------------------------------------------
template<int NW, int NZ, int NY, int ZT>
__global__ __launch_bounds__(256, 3) void conv_mfma(
    const float* __restrict__ in0, long bs0, const float* __restrict__ scale,
    const float* __restrict__ in1, long bs1,
    const _Float16* __restrict__ wt,
    const float* __restrict__ b1, const float* __restrict__ b2,
    float* __restrict__ out, int Cout)
{
    constexpr int NK = 8 / NZ;                      // K-iters (32 ci each)
    __shared__ alignas(16) _Float16 s_a[2][4 * PL * 8];

    const int tid = threadIdx.x;
    const int l = tid & 63, wv = tid >> 6;
    const int q = l >> 4, r = l & 15;

    // ---- XCD-aware slice decode (16 slices x 60 M-tiles = 960 blocks) ----
    const int lin = blockIdx.x;
    const int xcd = lin & 7;
    const int idx = lin >> 3;                       // 0..119 within XCD
    const int second = (idx >= 60) ? 1 : 0;
    const int sl = xcd * 2 + second;                // 0..15, slice = z*NY + y
    const int mb = idx - second * 60;               // M-tile 0..59
    const int zz = sl / NY;
    const int yy = sl - zz * NY;

    const int b = mb / 15;
    const int pix0 = (mb % 15) * 80;
    const int y0 = (mb % 15) * 2;
    const int n0 = yy * (4 * NW * 16) + wv * (NW * 16);
    const int src = zz / NZ;
    const int ci_start = (zz % NZ) * (CC / NZ);
    const int kgb0 = src * 288 + (ci_start >> 3);

    const float* inp = (src ? in1 + (size_t)b * bs1 : in0 + (size_t)b * bs0)
                       + (size_t)ci_start * HWS;
    const float* scl = (src == 0) ? scale : nullptr;

    // ---- per-thread staging geometry (3 items, fixed across K-loop) ----
    bool iv[3], pv[3];
    const float* pj[3];
    float sc[3];
    int ldsoff[3];
#pragma unroll
    for (int j = 0; j < 3; ++j) {
        int item = tid + j * 256;
        iv[j] = item < 672;
        int it = iv[j] ? item : 0;
        int cig = it / 168;
        int pix = it - cig * 168;
        int row = pix / 42;
        int px = pix - row * 42;
        int xx = px - 1, yy2 = y0 + row - 1;
        pv[j] = iv[j] && xx >= 0 && xx < WW && yy2 >= 0 && yy2 < HH;
        pj[j] = inp + (size_t)(cig * 8) * HWS + yy2 * WW + xx;
        sc[j] = 1.f;
        if (scl && pv[j]) sc[j] = scl[(size_t)b * HWS + yy2 * WW + xx];
        ldsoff[j] = (cig * PL + pix) * 8;
    }

    // ---- accumulators (bias folded into z==0 partial) ----
    f32x4 acc[5][NW];
#pragma unroll
    for (int nt = 0; nt < NW; ++nt) {
        int co = n0 + nt * 16 + r;
        float bias = (zz == 0) ? (b1[co] + b2[co]) : 0.f;
        f32x4 bv = {bias, bias, bias, bias};
#pragma unroll
        for (int mt = 0; mt < 5; ++mt) acc[mt][nt] = bv;
    }

    // ---- per-mt LDS pixel base (fold tap offset into ds_read immediate) ----
    int hbase[5];
#pragma unroll
    for (int mt = 0; mt < 5; ++mt) {
        int p = mt * 16 + r;
        int ry = p / 40;
        int rx = p - ry * 40;
        hbase[mt] = ry * 42 + rx;
    }

    // ---- staging pipeline: issue-early (before barrier), write-late ----
    float sr[3][8];
    auto stage_issue = [&](int kk) {
#pragma unroll
        for (int j = 0; j < 3; ++j) if (pv[j]) {
            const float* p0 = pj[j] + (size_t)kk * 32 * HWS;
#pragma unroll
            for (int t = 0; t < 8; ++t) sr[j][t] = p0[(size_t)t * HWS];
        }
    };
    auto stage_write = [&](int kk) {
#pragma unroll
        for (int j = 0; j < 3; ++j) if (iv[j]) {
            half8 hv = {0, 0, 0, 0, 0, 0, 0, 0};
            if (pv[j]) {
#pragma unroll
                for (int t = 0; t < 8; ++t)
                    hv[t] = (_Float16)(sr[j][t] * sc[j]);
            }
            *(half8*)&s_a[kk & 1][ldsoff[j]] = hv;
        }
    };

    const half8* wp = (const half8*)wt;
    half8 w0[NW], w1[NW], w2[NW], w3[NW];

#define WLOAD(SLOT, TAP) do {                                              \
    const int kg_ = kgb0 + k * 4 + (TAP) * 32 + q;                         \
    _Pragma("unroll")                                                      \
    for (int nt = 0; nt < NW; ++nt)                                        \
        SLOT[nt] = wp[(size_t)kg_ * Cout + n0 + nt * 16 + r];              \
} while (0)

#define CTAP(SLOT, TAP) do {                                               \
    constexpr int dy_ = (TAP) / 3, dx_ = (TAP) % 3;                        \
    _Pragma("unroll")                                                      \
    for (int mt = 0; mt < 5; ++mt) {                                       \
        half8 af = *(const half8*)&s_a[k & 1]                              \
            [(q * PL + hbase[mt] + dy_ * 42 + dx_) * 8];                   \
        _Pragma("unroll")                                                  \
        for (int nt = 0; nt < NW; ++nt)                                    \
            acc[mt][nt] = __builtin_amdgcn_mfma_f32_16x16x32_f16(          \
                af, SLOT[nt], acc[mt][nt], 0, 0, 0);                       \
    }                                                                      \
} while (0)

    // prologue: stage tile 0
    stage_issue(0);
    stage_write(0);

#pragma unroll
    for (int k = 0; k < NK; ++k) {
        WLOAD(w0, 0); WLOAD(w1, 1); WLOAD(w2, 2);    // taps 0-2, fly over barrier
        if (k + 1 < NK) stage_issue(k + 1);          // next act tile, fly over compute
        __syncthreads();                             // s_a[k&1] ready
        __builtin_amdgcn_s_setprio(1);
        WLOAD(w3, 3); CTAP(w0, 0);
        WLOAD(w0, 4); CTAP(w1, 1);
        WLOAD(w1, 5); CTAP(w2, 2);
        WLOAD(w2, 6); CTAP(w3, 3);
        WLOAD(w3, 7); CTAP(w0, 4);
        WLOAD(w0, 8); CTAP(w1, 5);
        __builtin_amdgcn_s_setprio(0);
        if (k + 1 < NK) stage_write(k + 1);          // land next tile mid-compute
        __builtin_amdgcn_s_setprio(1);
        CTAP(w2, 6);
        CTAP(w3, 7);
        CTAP(w0, 8);
        __builtin_amdgcn_s_setprio(0);
    }
#undef WLOAD
#undef CTAP

    out += (size_t)zz * BB * Cout * HWS;
#pragma unroll
    for (int mt = 0; mt < 5; ++mt) {
#pragma unroll
        for (int nt = 0; nt < NW; ++nt) {
            int co = n0 + nt * 16 + r;
            int p = pix0 + mt * 16 + q * 4;
            *(f32x4*)&out[((size_t)b * Cout + co) * HWS + p] = acc[mt][nt];
        }
    }
}

// ---------------------------------------------------------------------------
// att = tanh(a0 + a1 + a2 + a3)  (4 stacked K-split partials, float4 loads)
// ---------------------------------------------------------------------------
__global__ void add_tanh4(const float* __restrict__ a0,
                          float* __restrict__ o, int n4) {
    int id = blockIdx.x * 256 + threadIdx.x;
    if (id >= n4) return;
    const f32x4* av = (const f32x4*)a0;
    f32x4 s = av[id] + av[id + (size_t)n4] + av[id + 2 * (size_t)n4]
            + av[id + 3 * (size_t)n4];
    f32x4 rr;
#pragma unroll
    for (int j = 0; j < 4; ++j) rr[j] = tanhf(s[j]);
    ((f32x4*)o)[id] = rr;
}

// ---------------------------------------------------------------------------
// K-split attention score: part[b][ch][p] = sum_{ca in chunk ch} sum_tap
//   att[b,ca,y+dy-1,x+dx-1] * Va[tap,ca]
// ---------------------------------------------------------------------------
__global__ __launch_bounds__(256) void att_e_part(
    const float* __restrict__ att, const float* __restrict__ Va,
    float* __restrict__ part)
{
    __shared__ float red[4][64];
    const int lane = threadIdx.x & 63, wv = threadIdx.x >> 6;
    const int p = blockIdx.x * 64 + lane;
    const int b = blockIdx.y, ch = blockIdx.z;
    const bool valid = (p < HWS);
    const int pc = valid ? p : 0;
    const int y = pc / WW, x = pc - (pc / WW) * WW;

    float acc = 0.f;
    if (valid) {
        const int ca0 = ch * 32 + wv * 8;
#pragma unroll
        for (int j = 0; j < 8; ++j) {
            const int ca = ca0 + j;
            const float* base = att + ((size_t)b * CC + ca) * HWS;
            const float* va = Va + ca;
#pragma unroll
            for (int dy = 0; dy < 3; ++dy) {
                int yy = y + dy - 1;
                if (yy < 0 || yy >= HH) continue;
#pragma unroll
                for (int dx = 0; dx < 3; ++dx) {
                    int xx = x + dx - 1;
                    if (xx < 0 || xx >= WW) continue;
                    acc = fmaf(base[yy * WW + xx], va[(dy * 3 + dx) * CC], acc);
                }
            }
        }
    }
    red[wv][lane] = acc;
    __syncthreads();
    if (wv == 0 && valid)
        part[((size_t)b * 8 + ch) * HWS + p] =
            red[0][lane] + red[1][lane] + red[2][lane] + red[3][lane];
}

// ---------------------------------------------------------------------------
// softmax over HW per batch, summing the 8 K-split partials first (in LDS)
// ---------------------------------------------------------------------------
__global__ __launch_bounds__(256) void softmax_kernel(
    const float* __restrict__ part, float* __restrict__ a)
{
    __shared__ float se[HWS];
    __shared__ float red[256];
    int b = blockIdx.x;
    int tid = threadIdx.x;

    for (int i = tid; i < HWS; i += 256) {
        float s = 0.f;
#pragma unroll
        for (int ch = 0; ch < 8; ++ch)
            s += part[((size_t)b * 8 + ch) * HWS + i];
        se[i] = s;
    }
    __syncthreads();

    float m = -1e30f;
    for (int i = tid; i < HWS; i += 256) m = fmaxf(m, se[i]);
    red[tid] = m;
    __syncthreads();
    for (int s = 128; s > 0; s >>= 1) {
        if (tid < s) red[tid] = fmaxf(red[tid], red[tid + s]);
        __syncthreads();
    }
    m = red[0];
    __syncthreads();

    float sum = 0.f;
    for (int i = tid; i < HWS; i += 256) {
        float v = expf(se[i] - m);
        se[i] = v;
        sum += v;
    }
    red[tid] = sum;
    __syncthreads();
    for (int s = 128; s > 0; s >>= 1) {
        if (tid < s) red[tid] += red[tid + s];
        __syncthreads();
    }
    float inv = 1.f / red[0];
    for (int i = tid; i < HWS; i += 256)
        a[(size_t)b * HWS + i] = se[i] * inv;
}

// ---------------------------------------------------------------------------
// LSTM gate update, fusing the K-split partial sum: g = g0 + g1 (float4)
// ---------------------------------------------------------------------------
__global__ void gate_update(const float* __restrict__ g0, const float* __restrict__ g1,
                            float* __restrict__ c, float* __restrict__ h_out) {
    int id = blockIdx.x * 256 + threadIdx.x;
    if (id >= BB * CHW4) return;
    int b = id / CHW4;
    int rem = id - b * CHW4;
    const f32x4* g0v = (const f32x4*)g0;
    const f32x4* g1v = (const f32x4*)g1;
    size_t gb = (size_t)b * 4 * CHW4 + rem;
    f32x4 gi = g0v[gb] + g1v[gb];
    f32x4 gf = g0v[gb + CHW4] + g1v[gb + CHW4];
    f32x4 gc = g0v[gb + 2 * (size_t)CHW4] + g1v[gb + 2 * (size_t)CHW4];
    f32x4 go = g0v[gb + 3 * (size_t)CHW4] + g1v[gb + 3 * (size_t)CHW4];
    f32x4 cv = ((const f32x4*)c)[id];
    f32x4 cn, hn;
#pragma unroll
    for (int j = 0; j < 4; ++j) {
        float i_ = 1.f / (1.f + expf(-gi[j]));
        float f_ = 1.f / (1.f + expf(-gf[j]));
        float o_ = 1.f / (1.f + expf(-go[j]));
        float cc = f_ * cv[j] + i_ * tanhf(gc[j]);
        cn[j] = cc;
        hn[j] = o_ * tanhf(cc);
    }
    ((f32x4*)c)[id] = cn;
    ((f32x4*)h_out)[id] = hn;
}

// ---------------------------------------------------------------------------
extern "C" void kernel_launch(void* const* d_in, const int* in_sizes, int n_in,
                              void* d_out, int out_size, void* d_ws, size_t ws_size,
                              hipStream_t stream) {
    const float* x   = (const float*)d_in[0];
    const float* Wa  = (const float*)d_in[1];
    const float* ba  = (const float*)d_in[2];
    const float* Ua  = (const float*)d_in[3];
    const float* bua = (const float*)d_in[4];
    const float* Va  = (const float*)d_in[5];
    const float* Wx  = (const float*)d_in[6];
    const float* bx  = (const float*)d_in[7];
    const float* Uh  = (const float*)d_in[8];
    const float* bh  = (const float*)d_in[9];
    float* out = (float*)d_out;

    char* wsb = (char*)d_ws;
    const size_t NCHW = (size_t)BB * CHW;
    _Float16* wtg = (_Float16*)wsb;               wsb += (size_t)4608 * 1024 * 2;
    _Float16* wta = (_Float16*)wsb;               wsb += (size_t)4608 * 256 * 2;
    float* h0   = (float*)wsb;                    wsb += NCHW * 4;
    float* h1   = (float*)wsb;                    wsb += NCHW * 4;
    float* cb   = (float*)wsb;                    wsb += NCHW * 4;
    float* g01  = (float*)wsb;                    wsb += 8 * NCHW * 4;   // z-stacked
    float* att  = (float*)wsb;                    wsb += NCHW * 4;
    float* part = (float*)wsb;                    wsb += (size_t)BB * 8 * HWS * 4;
    float* a    = (float*)wsb;
    // att01 (4 z-stacked partials) aliases g01: lifetimes are disjoint
    // within a timestep (att01 dead after add_tanh4, g01 born at conv<2>).
    float* att01 = g01;

    pack_weights<<<dim3((4608 * 1024 + 255) / 256), dim3(256), 0, stream>>>(
        Wx, Uh, wtg, 1024);
    pack_weights<<<dim3((4608 * 256 + 255) / 256), dim3(256), 0, stream>>>(
        Wa, Ua, wta, 256);

    const int n4 = BB * CHW4;
    init_hc<<<dim3((n4 + 255) / 256), dim3(256), 0, stream>>>(x, h0, cb);

    float* hbuf[2] = {h0, h1};
    const long XT_BS = (long)TT * CHW;
    const long H_BS  = (long)CHW;

    for (int t = 0; t < TT; ++t) {
        const float* xt = x + (size_t)t * CHW;
        float* hcur = hbuf[t & 1];
        float* hnext = (t == TT - 1) ? out : hbuf[(t + 1) & 1];

        // attention partials, XCD-swizzled flat grid (16 slices x 60 tiles):
        //   z in {0,1}: conv(h, Wa) ci-halves (z=0 carries bias)
        //   z in {2,3}: conv(xt, Ua) ci-halves
        conv_mfma<1, 2, 4, 4><<<dim3(960), dim3(256), 0, stream>>>(
            hcur, H_BS, nullptr, xt, XT_BS, wta, ba, bua, att01, 256);
        add_tanh4<<<dim3((n4 + 255) / 256), dim3(256), 0, stream>>>(
            att01, att, n4);

        // e-partials (K-split over ca) + softmax (sums partials)
        att_e_part<<<dim3(19, BB, 8), dim3(256), 0, stream>>>(att, Va, part);
        softmax_kernel<<<dim3(BB), dim3(256), 0, stream>>>(part, a);

        // gates, XCD-swizzled flat grid (16 slices x 60 tiles):
        //   z=0: conv(xt*a, Wx)+bx+bh ; z=1: conv(h, Uh)
        conv_mfma<2, 1, 8, 2><<<dim3(960), dim3(256), 0, stream>>>(
            xt, XT_BS, a, hcur, H_BS, wtg, bx, bh, g01, 1024);

        gate_update<<<dim3((n4 + 255) / 256), dim3(256), 0, stream>>>(
            g01, g01 + 4 * NCHW, cb, hnext);
    }
}

// Round 3
// 562.985 us; speedup vs baseline: 1.0947x; 1.0947x over previous
//
#include <hip/hip_runtime.h>
#include <math.h>

#define BB 4
#define TT 4
#define CC 256
#define HH 30
#define WW 40
#define HWS (HH*WW)          // 1200
#define CHW (CC*HWS)         // 307200
#define CHW4 (CHW/4)
#define NCG 32               // ci-groups of 8
#define PXS (NCG*HWS*8)      // f16 elements per blocked image [32][1200][8] = 307200
#define PL 168               // LDS plane stride in pixels

typedef __attribute__((ext_vector_type(8))) _Float16 half8;
typedef __attribute__((ext_vector_type(4))) float f32x4;

// ---------------------------------------------------------------------------
// Pack x (all B,T) to f16 blocked pixel-major: x16[b][t][cig][p][8]
// ---------------------------------------------------------------------------
__global__ void pack_x16(const float* __restrict__ x, _Float16* __restrict__ x16) {
    int id = blockIdx.x * 256 + threadIdx.x;
    if (id >= BB * TT * NCG * HWS) return;
    int p = id % HWS;
    int cig = (id / HWS) % NCG;
    int bt = id / (HWS * NCG);
    const float* src = x + ((size_t)bt * CC + cig * 8) * HWS + p;
    half8 hv;
#pragma unroll
    for (int j = 0; j < 8; ++j) hv[j] = (_Float16)src[(size_t)j * HWS];
    *(half8*)&x16[(size_t)id * 8] = hv;
}

// ---------------------------------------------------------------------------
// h0 = sum_t x; c0 = h0.  c stays f32 [B][C][HW]; h emitted f16 blocked.
// ---------------------------------------------------------------------------
__global__ void init_hc(const float* __restrict__ x, _Float16* __restrict__ h16,
                        float* __restrict__ c) {
    int id = blockIdx.x * 256 + threadIdx.x;
    if (id >= BB * NCG * HWS) return;
    int p = id % HWS;
    int cig = (id / HWS) % NCG;
    int b = id / (HWS * NCG);
    float s[8];
#pragma unroll
    for (int j = 0; j < 8; ++j) s[j] = 0.f;
#pragma unroll
    for (int t = 0; t < TT; ++t) {
        const float* src = x + (((size_t)b * TT + t) * CC + cig * 8) * HWS + p;
#pragma unroll
        for (int j = 0; j < 8; ++j) s[j] += src[(size_t)j * HWS];
    }
    half8 hv;
    float* cp = c + ((size_t)b * CC + cig * 8) * HWS + p;
#pragma unroll
    for (int j = 0; j < 8; ++j) { cp[(size_t)j * HWS] = s[j]; hv[j] = (_Float16)s[j]; }
    *(half8*)&h16[(size_t)id * 8] = hv;
}

// ---------------------------------------------------------------------------
// xtilde16[b][cig][p][8] = (f16)(x_f32[b,t,ci,p] * a[b,p])  — same rounding as
// the old in-staging (f16)(x*sc), so numerics are unchanged.
// ---------------------------------------------------------------------------
__global__ void xtilde_kernel(const float* __restrict__ xt, const float* __restrict__ a,
                              _Float16* __restrict__ xt16) {
    int id = blockIdx.x * 256 + threadIdx.x;
    if (id >= BB * NCG * HWS) return;
    int p = id % HWS;
    int cig = (id / HWS) % NCG;
    int b = id / (HWS * NCG);
    float sc = a[(size_t)b * HWS + p];
    const float* src = xt + ((size_t)b * TT * CC + cig * 8) * HWS + p;
    half8 hv;
#pragma unroll
    for (int j = 0; j < 8; ++j) hv[j] = (_Float16)(src[(size_t)j * HWS] * sc);
    *(half8*)&xt16[(size_t)id * 8] = hv;
}

// ---------------------------------------------------------------------------
// Pack weights to f16: layout [kg=k/8][Cout][k%8]
// ---------------------------------------------------------------------------
__global__ void pack_weights(const float* __restrict__ W1,
                             const float* __restrict__ W2,
                             _Float16* __restrict__ wt, int Cout) {
    int idx = blockIdx.x * 256 + threadIdx.x;
    if (idx >= 4608 * Cout) return;
    int k = idx / Cout;
    int n = idx - k * Cout;
    float v = (k < 2304) ? W1[(size_t)k * Cout + n]
                         : W2[(size_t)(k - 2304) * Cout + n];
    wt[((size_t)(k >> 3) * Cout + n) * 8 + (k & 7)] = (_Float16)v;
}

// ---------------------------------------------------------------------------
// MFMA dual 3x3 conv, f16 blocked activations [cig][1200][8].
// 16 slices (y-chunk, z=(src,ci-chunk)); 60 M-tiles each; XCD-homed decode:
// XCD i (= id&7) owns slices {2i,2i+1} -> weights AND activation source are
// per-XCD L2-resident.
// Kiter body: ONE barrier, no mid-loop fence. Staging = 3x pure b128 copy
// (issue one kiter early, ds_write at end of kiter into the other buffer).
// ---------------------------------------------------------------------------
template<int NW, int NZ, int NY, int ZT>
__global__ __launch_bounds__(256, 4) void conv_mfma(
    const _Float16* __restrict__ in0, long bs0,
    const _Float16* __restrict__ in1, long bs1,
    const _Float16* __restrict__ wt,
    const float* __restrict__ b1, const float* __restrict__ b2,
    float* __restrict__ out, int Cout)
{
    constexpr int NK = 8 / NZ;                      // K-iters (32 ci each)
    __shared__ alignas(16) _Float16 s_a[2][4 * PL * 8];

    const int tid = threadIdx.x;
    const int l = tid & 63, wv = tid >> 6;
    const int q = l >> 4, r = l & 15;

    // ---- XCD-aware slice decode (16 slices x 60 M-tiles = 960 blocks) ----
    const int lin = blockIdx.x;
    const int xcd = lin & 7;
    const int idx = lin >> 3;                       // 0..119 within XCD
    const int second = (idx >= 60) ? 1 : 0;
    const int sl = xcd * 2 + second;                // slice = z*NY + y
    const int mb = idx - second * 60;               // M-tile 0..59
    const int zz = sl / NY;
    const int yy = sl - zz * NY;

    const int b = mb / 15;
    const int pix0 = (mb % 15) * 80;
    const int y0 = (mb % 15) * 2;
    const int n0 = yy * (4 * NW * 16) + wv * (NW * 16);
    const int src = zz / NZ;
    const int ci_start = (zz % NZ) * (CC / NZ);
    const int kgb0 = src * 288 + (ci_start >> 3);

    const _Float16* inp = src ? (in1 + (size_t)b * bs1) : (in0 + (size_t)b * bs0);

    // ---- per-thread staging geometry (3 items, fixed across K-loop) ----
    bool iv[3], pv[3];
    const _Float16* pj[3];
    int ldsoff[3];
#pragma unroll
    for (int j = 0; j < 3; ++j) {
        int item = tid + j * 256;
        iv[j] = item < 672;
        int it = iv[j] ? item : 0;
        int cig = it / 168;
        int pix = it - cig * 168;
        int row = pix / 42;
        int px = pix - row * 42;
        int xx = px - 1, yy2 = y0 + row - 1;
        pv[j] = iv[j] && xx >= 0 && xx < WW && yy2 >= 0 && yy2 < HH;
        pj[j] = inp + ((size_t)((ci_start >> 3) + cig) * HWS + yy2 * WW + xx) * 8;
        ldsoff[j] = (cig * PL + pix) * 8;
    }

    // ---- accumulators (bias folded into z==0 partial) ----
    f32x4 acc[5][NW];
#pragma unroll
    for (int nt = 0; nt < NW; ++nt) {
        int co = n0 + nt * 16 + r;
        float bias = (zz == 0) ? (b1[co] + b2[co]) : 0.f;
        f32x4 bv = {bias, bias, bias, bias};
#pragma unroll
        for (int mt = 0; mt < 5; ++mt) acc[mt][nt] = bv;
    }

    // ---- per-mt LDS pixel base ----
    int hbase[5];
#pragma unroll
    for (int mt = 0; mt < 5; ++mt) {
        int p = mt * 16 + r;
        int ry = p / 40;
        int rx = p - ry * 40;
        hbase[mt] = ry * 42 + rx;
    }

    // ---- staging: pure b128 copy; issue early, write at end of kiter ----
    half8 sr[3];
    auto stage_issue = [&](int kk) {
#pragma unroll
        for (int j = 0; j < 3; ++j) if (pv[j])
            sr[j] = *(const half8*)(pj[j] + (size_t)kk * (4 * HWS * 8));
    };
    auto stage_write = [&](int kk) {
#pragma unroll
        for (int j = 0; j < 3; ++j) if (iv[j]) {
            half8 hv = {0, 0, 0, 0, 0, 0, 0, 0};
            if (pv[j]) hv = sr[j];
            *(half8*)&s_a[kk & 1][ldsoff[j]] = hv;
        }
    };

    const half8* wp = (const half8*)wt;
    half8 w0[NW], w1[NW], w2[NW], w3[NW];

#define WLOAD(SLOT, TAP) do {                                              \
    const int kg_ = kgb0 + k * 4 + (TAP) * 32 + q;                         \
    _Pragma("unroll")                                                      \
    for (int nt = 0; nt < NW; ++nt)                                        \
        SLOT[nt] = wp[(size_t)kg_ * Cout + n0 + nt * 16 + r];              \
} while (0)

#define CTAP(SLOT, TAP) do {                                               \
    constexpr int dy_ = (TAP) / 3, dx_ = (TAP) % 3;                        \
    _Pragma("unroll")                                                      \
    for (int mt = 0; mt < 5; ++mt) {                                       \
        half8 af = *(const half8*)&s_a[k & 1]                              \
            [(q * PL + hbase[mt] + dy_ * 42 + dx_) * 8];                   \
        _Pragma("unroll")                                                  \
        for (int nt = 0; nt < NW; ++nt)                                    \
            acc[mt][nt] = __builtin_amdgcn_mfma_f32_16x16x32_f16(          \
                af, SLOT[nt], acc[mt][nt], 0, 0, 0);                       \
    }                                                                      \
} while (0)

    // prologue: stage tile 0
    stage_issue(0);
    stage_write(0);

#pragma unroll
    for (int k = 0; k < NK; ++k) {
        WLOAD(w0, 0); WLOAD(w1, 1); WLOAD(w2, 2);    // taps 0-2 fly over barrier
        if (k + 1 < NK) stage_issue(k + 1);          // next-tile loads fly over compute
        __syncthreads();                             // s_a[k&1] ready
        __builtin_amdgcn_s_setprio(1);
        WLOAD(w3, 3); CTAP(w0, 0);
        WLOAD(w0, 4); CTAP(w1, 1);
        WLOAD(w1, 5); CTAP(w2, 2);
        WLOAD(w2, 6); CTAP(w3, 3);
        WLOAD(w3, 7); CTAP(w0, 4);
        WLOAD(w0, 8); CTAP(w1, 5);
        CTAP(w2, 6);
        CTAP(w3, 7);
        CTAP(w0, 8);
        __builtin_amdgcn_s_setprio(0);
        if (k + 1 < NK) stage_write(k + 1);          // land next tile; other buffer,
                                                     // so no fence on this kiter
    }
#undef WLOAD
#undef CTAP

    out += (size_t)zz * BB * Cout * HWS;
#pragma unroll
    for (int mt = 0; mt < 5; ++mt) {
#pragma unroll
        for (int nt = 0; nt < NW; ++nt) {
            int co = n0 + nt * 16 + r;
            int p = pix0 + mt * 16 + q * 4;
            *(f32x4*)&out[((size_t)b * Cout + co) * HWS + p] = acc[mt][nt];
        }
    }
}

// ---------------------------------------------------------------------------
// att = tanh(a0 + a1 + a2 + a3)  (4 stacked K-split partials, float4 loads)
// ---------------------------------------------------------------------------
__global__ void add_tanh4(const float* __restrict__ a0,
                          float* __restrict__ o, int n4) {
    int id = blockIdx.x * 256 + threadIdx.x;
    if (id >= n4) return;
    const f32x4* av = (const f32x4*)a0;
    f32x4 s = av[id] + av[id + (size_t)n4] + av[id + 2 * (size_t)n4]
            + av[id + 3 * (size_t)n4];
    f32x4 rr;
#pragma unroll
    for (int j = 0; j < 4; ++j) rr[j] = tanhf(s[j]);
    ((f32x4*)o)[id] = rr;
}

// ---------------------------------------------------------------------------
// K-split attention score: part[b][ch][p] = sum_{ca in chunk} sum_tap
//   att[b,ca,y+dy-1,x+dx-1] * Va[tap,ca]
// ---------------------------------------------------------------------------
__global__ __launch_bounds__(256) void att_e_part(
    const float* __restrict__ att, const float* __restrict__ Va,
    float* __restrict__ part)
{
    __shared__ float red[4][64];
    const int lane = threadIdx.x & 63, wv = threadIdx.x >> 6;
    const int p = blockIdx.x * 64 + lane;
    const int b = blockIdx.y, ch = blockIdx.z;
    const bool valid = (p < HWS);
    const int pc = valid ? p : 0;
    const int y = pc / WW, x = pc - (pc / WW) * WW;

    float acc = 0.f;
    if (valid) {
        const int ca0 = ch * 32 + wv * 8;
#pragma unroll
        for (int j = 0; j < 8; ++j) {
            const int ca = ca0 + j;
            const float* base = att + ((size_t)b * CC + ca) * HWS;
            const float* va = Va + ca;
#pragma unroll
            for (int dy = 0; dy < 3; ++dy) {
                int yy = y + dy - 1;
                if (yy < 0 || yy >= HH) continue;
#pragma unroll
                for (int dx = 0; dx < 3; ++dx) {
                    int xx = x + dx - 1;
                    if (xx < 0 || xx >= WW) continue;
                    acc = fmaf(base[yy * WW + xx], va[(dy * 3 + dx) * CC], acc);
                }
            }
        }
    }
    red[wv][lane] = acc;
    __syncthreads();
    if (wv == 0 && valid)
        part[((size_t)b * 8 + ch) * HWS + p] =
            red[0][lane] + red[1][lane] + red[2][lane] + red[3][lane];
}

// ---------------------------------------------------------------------------
// softmax over HW per batch, summing the 8 K-split partials first (in LDS)
// ---------------------------------------------------------------------------
__global__ __launch_bounds__(256) void softmax_kernel(
    const float* __restrict__ part, float* __restrict__ a)
{
    __shared__ float se[HWS];
    __shared__ float red[256];
    int b = blockIdx.x;
    int tid = threadIdx.x;

    for (int i = tid; i < HWS; i += 256) {
        float s = 0.f;
#pragma unroll
        for (int ch = 0; ch < 8; ++ch)
            s += part[((size_t)b * 8 + ch) * HWS + i];
        se[i] = s;
    }
    __syncthreads();

    float m = -1e30f;
    for (int i = tid; i < HWS; i += 256) m = fmaxf(m, se[i]);
    red[tid] = m;
    __syncthreads();
    for (int s = 128; s > 0; s >>= 1) {
        if (tid < s) red[tid] = fmaxf(red[tid], red[tid + s]);
        __syncthreads();
    }
    m = red[0];
    __syncthreads();

    float sum = 0.f;
    for (int i = tid; i < HWS; i += 256) {
        float v = expf(se[i] - m);
        se[i] = v;
        sum += v;
    }
    red[tid] = sum;
    __syncthreads();
    for (int s = 128; s > 0; s >>= 1) {
        if (tid < s) red[tid] += red[tid + s];
        __syncthreads();
    }
    float inv = 1.f / red[0];
    for (int i = tid; i < HWS; i += 256)
        a[(size_t)b * HWS + i] = se[i] * inv;
}

// ---------------------------------------------------------------------------
// LSTM gate update; emits h16 (blocked f16) always, h f32 only on last step.
// Thread = (b, cig, p): 8 ci at one pixel (loads coalesced per plane).
// ---------------------------------------------------------------------------
__global__ void gate_update(const float* __restrict__ g0, const float* __restrict__ g1,
                            float* __restrict__ c, _Float16* __restrict__ h16,
                            float* __restrict__ h32) {
    int id = blockIdx.x * 256 + threadIdx.x;
    if (id >= BB * NCG * HWS) return;
    int p = id % HWS;
    int cig = (id / HWS) % NCG;
    int b = id / (HWS * NCG);
    const int ci0 = cig * 8;
    half8 hv;
#pragma unroll
    for (int j = 0; j < 8; ++j) {
        size_t base = ((size_t)b * 4 * CC + ci0 + j) * HWS + p;
        float gi = g0[base] + g1[base];
        float gf = g0[base + (size_t)CHW] + g1[base + (size_t)CHW];
        float gc = g0[base + 2 * (size_t)CHW] + g1[base + 2 * (size_t)CHW];
        float go = g0[base + 3 * (size_t)CHW] + g1[base + 3 * (size_t)CHW];
        float i_ = 1.f / (1.f + expf(-gi));
        float f_ = 1.f / (1.f + expf(-gf));
        float o_ = 1.f / (1.f + expf(-go));
        size_t cix = ((size_t)b * CC + ci0 + j) * HWS + p;
        float cn = f_ * c[cix] + i_ * tanhf(gc);
        c[cix] = cn;
        float hn = o_ * tanhf(cn);
        hv[j] = (_Float16)hn;
        if (h32) h32[cix] = hn;
    }
    *(half8*)&h16[(size_t)id * 8] = hv;
}

// ---------------------------------------------------------------------------
extern "C" void kernel_launch(void* const* d_in, const int* in_sizes, int n_in,
                              void* d_out, int out_size, void* d_ws, size_t ws_size,
                              hipStream_t stream) {
    const float* x   = (const float*)d_in[0];
    const float* Wa  = (const float*)d_in[1];
    const float* ba  = (const float*)d_in[2];
    const float* Ua  = (const float*)d_in[3];
    const float* bua = (const float*)d_in[4];
    const float* Va  = (const float*)d_in[5];
    const float* Wx  = (const float*)d_in[6];
    const float* bx  = (const float*)d_in[7];
    const float* Uh  = (const float*)d_in[8];
    const float* bh  = (const float*)d_in[9];
    float* out = (float*)d_out;

    char* wsb = (char*)d_ws;
    const size_t NCHW = (size_t)BB * CHW;
    _Float16* wtg  = (_Float16*)wsb;              wsb += (size_t)4608 * 1024 * 2;
    _Float16* wta  = (_Float16*)wsb;              wsb += (size_t)4608 * 256 * 2;
    _Float16* x16  = (_Float16*)wsb;              wsb += (size_t)BB * TT * PXS * 2;
    _Float16* h16  = (_Float16*)wsb;              wsb += (size_t)BB * PXS * 2;
    _Float16* xt16 = (_Float16*)wsb;              wsb += (size_t)BB * PXS * 2;
    float* cb   = (float*)wsb;                    wsb += NCHW * 4;
    float* g01  = (float*)wsb;                    wsb += 8 * NCHW * 4;   // z-stacked
    float* att  = (float*)wsb;                    wsb += NCHW * 4;
    float* part = (float*)wsb;                    wsb += (size_t)BB * 8 * HWS * 4;
    float* a    = (float*)wsb;
    // att01 (4 z-stacked partials, Cout=256) aliases g01 (disjoint lifetime)
    float* att01 = g01;

    pack_weights<<<dim3((4608 * 1024 + 255) / 256), dim3(256), 0, stream>>>(
        Wx, Uh, wtg, 1024);
    pack_weights<<<dim3((4608 * 256 + 255) / 256), dim3(256), 0, stream>>>(
        Wa, Ua, wta, 256);
    pack_x16<<<dim3((BB * TT * NCG * HWS + 255) / 256), dim3(256), 0, stream>>>(
        x, x16);

    const int nblk = BB * NCG * HWS;              // 153600
    init_hc<<<dim3((nblk + 255) / 256), dim3(256), 0, stream>>>(x, h16, cb);

    const int n4 = (int)(NCHW / 4);

    for (int t = 0; t < TT; ++t) {
        // attention partials: z∈{0,1}: conv(h16, Wa) ci-halves (z=0 + bias)
        //                     z∈{2,3}: conv(x16[t], Ua) ci-halves
        conv_mfma<1, 2, 4, 4><<<dim3(960), dim3(256), 0, stream>>>(
            h16, (long)PXS, x16 + (size_t)t * PXS, (long)TT * PXS,
            wta, ba, bua, att01, 256);
        add_tanh4<<<dim3((n4 + 255) / 256), dim3(256), 0, stream>>>(
            att01, att, n4);

        att_e_part<<<dim3(19, BB, 8), dim3(256), 0, stream>>>(att, Va, part);
        softmax_kernel<<<dim3(BB), dim3(256), 0, stream>>>(part, a);

        // x_tilde in f16 blocked (exact same rounding as old in-staging path)
        xtilde_kernel<<<dim3((nblk + 255) / 256), dim3(256), 0, stream>>>(
            x + (size_t)t * CHW, a, xt16);

        // gates: z=0: conv(xt16, Wx)+bx+bh ; z=1: conv(h16, Uh)
        conv_mfma<2, 1, 8, 2><<<dim3(960), dim3(256), 0, stream>>>(
            xt16, (long)PXS, h16, (long)PXS, wtg, bx, bh, g01, 1024);

        gate_update<<<dim3((nblk + 255) / 256), dim3(256), 0, stream>>>(
            g01, g01 + 4 * NCHW, cb, h16, (t == TT - 1) ? out : nullptr);
    }
}

// Round 4
// 561.050 us; speedup vs baseline: 1.0984x; 1.0034x over previous
//
#include <hip/hip_runtime.h>
#include <math.h>

#define BB 4
#define TT 4
#define CC 256
#define HH 30
#define WW 40
#define HWS (HH*WW)          // 1200
#define CHW (CC*HWS)         // 307200
#define CHW4 (CHW/4)
#define NCG 32               // ci-groups of 8
#define PXS (NCG*HWS*8)      // f16 elements per blocked image [32][1200][8] = 307200
#define PL 168               // LDS plane stride in pixels

typedef __attribute__((ext_vector_type(8))) _Float16 half8;
typedef __attribute__((ext_vector_type(4))) float f32x4;

// ---------------------------------------------------------------------------
// Pack x (all B,T) to f16 blocked pixel-major: x16[b][t][cig][p][8]
// ---------------------------------------------------------------------------
__global__ void pack_x16(const float* __restrict__ x, _Float16* __restrict__ x16) {
    int id = blockIdx.x * 256 + threadIdx.x;
    if (id >= BB * TT * NCG * HWS) return;
    int p = id % HWS;
    int cig = (id / HWS) % NCG;
    int bt = id / (HWS * NCG);
    const float* src = x + ((size_t)bt * CC + cig * 8) * HWS + p;
    half8 hv;
#pragma unroll
    for (int j = 0; j < 8; ++j) hv[j] = (_Float16)src[(size_t)j * HWS];
    *(half8*)&x16[(size_t)id * 8] = hv;
}

// ---------------------------------------------------------------------------
// h0 = sum_t x; c0 = h0.  c stays f32 [B][C][HW]; h emitted f16 blocked.
// ---------------------------------------------------------------------------
__global__ void init_hc(const float* __restrict__ x, _Float16* __restrict__ h16,
                        float* __restrict__ c) {
    int id = blockIdx.x * 256 + threadIdx.x;
    if (id >= BB * NCG * HWS) return;
    int p = id % HWS;
    int cig = (id / HWS) % NCG;
    int b = id / (HWS * NCG);
    float s[8];
#pragma unroll
    for (int j = 0; j < 8; ++j) s[j] = 0.f;
#pragma unroll
    for (int t = 0; t < TT; ++t) {
        const float* src = x + (((size_t)b * TT + t) * CC + cig * 8) * HWS + p;
#pragma unroll
        for (int j = 0; j < 8; ++j) s[j] += src[(size_t)j * HWS];
    }
    half8 hv;
    float* cp = c + ((size_t)b * CC + cig * 8) * HWS + p;
#pragma unroll
    for (int j = 0; j < 8; ++j) { cp[(size_t)j * HWS] = s[j]; hv[j] = (_Float16)s[j]; }
    *(half8*)&h16[(size_t)id * 8] = hv;
}

// ---------------------------------------------------------------------------
// xtilde16[b][cig][p][8] = (f16)(x_f32[b,t,ci,p] * a[b,p])
// ---------------------------------------------------------------------------
__global__ void xtilde_kernel(const float* __restrict__ xt, const float* __restrict__ a,
                              _Float16* __restrict__ xt16) {
    int id = blockIdx.x * 256 + threadIdx.x;
    if (id >= BB * NCG * HWS) return;
    int p = id % HWS;
    int cig = (id / HWS) % NCG;
    int b = id / (HWS * NCG);
    float sc = a[(size_t)b * HWS + p];
    const float* src = xt + ((size_t)b * TT * CC + cig * 8) * HWS + p;
    half8 hv;
#pragma unroll
    for (int j = 0; j < 8; ++j) hv[j] = (_Float16)(src[(size_t)j * HWS] * sc);
    *(half8*)&xt16[(size_t)id * 8] = hv;
}

// ---------------------------------------------------------------------------
// Pack weights to f16: layout [kg=k/8][Cout][k%8]
// ---------------------------------------------------------------------------
__global__ void pack_weights(const float* __restrict__ W1,
                             const float* __restrict__ W2,
                             _Float16* __restrict__ wt, int Cout) {
    int idx = blockIdx.x * 256 + threadIdx.x;
    if (idx >= 4608 * Cout) return;
    int k = idx / Cout;
    int n = idx - k * Cout;
    float v = (k < 2304) ? W1[(size_t)k * Cout + n]
                         : W2[(size_t)(k - 2304) * Cout + n];
    wt[((size_t)(k >> 3) * Cout + n) * 8 + (k & 7)] = (_Float16)v;
}

// ---------------------------------------------------------------------------
// MFMA dual 3x3 conv, f16 blocked activations [cig][1200][8].
// SLICES = NY*ZT work slices (y = cout-chunk, z = (src, ci-chunk));
// 60 M-tiles per slice. XCD-homed flat grid: XCD i (= id&7) owns
// SLICES/8 slices -> weights + activation source L2-resident per XCD.
// NW couts-tiles per wave: each A-fragment ds_read feeds NW MFMAs
// (NW=4 drops LDS-read demand below the MFMA pipe demand).
// Kiter body: ONE barrier, no mid-loop fence; staging = 3x pure b128 copy.
// ---------------------------------------------------------------------------
template<int NW, int NZ, int NY, int ZT>
__global__ __launch_bounds__(256, 2) void conv_mfma(
    const _Float16* __restrict__ in0, long bs0,
    const _Float16* __restrict__ in1, long bs1,
    const _Float16* __restrict__ wt,
    const float* __restrict__ b1, const float* __restrict__ b2,
    float* __restrict__ out, int Cout)
{
    constexpr int NK = 8 / NZ;                      // K-iters (32 ci each)
    constexpr int SLICES = NY * ZT;                 // 8 or 16
    constexpr int PERX = SLICES / 8;                // slices per XCD
    __shared__ alignas(16) _Float16 s_a[2][4 * PL * 8];

    const int tid = threadIdx.x;
    const int l = tid & 63, wv = tid >> 6;
    const int q = l >> 4, r = l & 15;

    // ---- XCD-homed slice decode (60*SLICES blocks) ----
    const int lin = blockIdx.x;
    const int xcd = lin & 7;
    const int idx = lin >> 3;                       // 0..60*PERX-1 within XCD
    const int sl = xcd * PERX + idx / 60;           // slice = z*NY + y
    const int mb = idx % 60;                        // M-tile 0..59
    const int zz = sl / NY;
    const int yy = sl - zz * NY;

    const int b = mb / 15;
    const int pix0 = (mb % 15) * 80;
    const int y0 = (mb % 15) * 2;
    const int n0 = yy * (4 * NW * 16) + wv * (NW * 16);
    const int src = zz / NZ;
    const int ci_start = (zz % NZ) * (CC / NZ);
    const int kgb0 = src * 288 + (ci_start >> 3);

    const _Float16* inp = src ? (in1 + (size_t)b * bs1) : (in0 + (size_t)b * bs0);

    // ---- per-thread staging geometry (3 items, fixed across K-loop) ----
    bool iv[3], pv[3];
    const _Float16* pj[3];
    int ldsoff[3];
#pragma unroll
    for (int j = 0; j < 3; ++j) {
        int item = tid + j * 256;
        iv[j] = item < 672;
        int it = iv[j] ? item : 0;
        int cig = it / 168;
        int pix = it - cig * 168;
        int row = pix / 42;
        int px = pix - row * 42;
        int xx = px - 1, yy2 = y0 + row - 1;
        pv[j] = iv[j] && xx >= 0 && xx < WW && yy2 >= 0 && yy2 < HH;
        pj[j] = inp + ((size_t)((ci_start >> 3) + cig) * HWS + yy2 * WW + xx) * 8;
        ldsoff[j] = (cig * PL + pix) * 8;
    }

    // ---- accumulators (bias folded into z==0 partial) ----
    f32x4 acc[5][NW];
#pragma unroll
    for (int nt = 0; nt < NW; ++nt) {
        int co = n0 + nt * 16 + r;
        float bias = (zz == 0) ? (b1[co] + b2[co]) : 0.f;
        f32x4 bv = {bias, bias, bias, bias};
#pragma unroll
        for (int mt = 0; mt < 5; ++mt) acc[mt][nt] = bv;
    }

    // ---- per-mt LDS pixel base ----
    int hbase[5];
#pragma unroll
    for (int mt = 0; mt < 5; ++mt) {
        int p = mt * 16 + r;
        int ry = p / 40;
        int rx = p - ry * 40;
        hbase[mt] = ry * 42 + rx;
    }

    // ---- staging: pure b128 copy; issue early, write at end of kiter ----
    half8 sr[3];
    auto stage_issue = [&](int kk) {
#pragma unroll
        for (int j = 0; j < 3; ++j) if (pv[j])
            sr[j] = *(const half8*)(pj[j] + (size_t)kk * (4 * HWS * 8));
    };
    auto stage_write = [&](int kk) {
#pragma unroll
        for (int j = 0; j < 3; ++j) if (iv[j]) {
            half8 hv = {0, 0, 0, 0, 0, 0, 0, 0};
            if (pv[j]) hv = sr[j];
            *(half8*)&s_a[kk & 1][ldsoff[j]] = hv;
        }
    };

    const half8* wp = (const half8*)wt;
    half8 w0[NW], w1[NW], w2[NW], w3[NW];

#define WLOAD(SLOT, TAP) do {                                              \
    const int kg_ = kgb0 + k * 4 + (TAP) * 32 + q;                         \
    _Pragma("unroll")                                                      \
    for (int nt = 0; nt < NW; ++nt)                                        \
        SLOT[nt] = wp[(size_t)kg_ * Cout + n0 + nt * 16 + r];              \
} while (0)

#define CTAP(SLOT, TAP) do {                                               \
    constexpr int dy_ = (TAP) / 3, dx_ = (TAP) % 3;                        \
    _Pragma("unroll")                                                      \
    for (int mt = 0; mt < 5; ++mt) {                                       \
        half8 af = *(const half8*)&s_a[k & 1]                              \
            [(q * PL + hbase[mt] + dy_ * 42 + dx_) * 8];                   \
        _Pragma("unroll")                                                  \
        for (int nt = 0; nt < NW; ++nt)                                    \
            acc[mt][nt] = __builtin_amdgcn_mfma_f32_16x16x32_f16(          \
                af, SLOT[nt], acc[mt][nt], 0, 0, 0);                       \
    }                                                                      \
} while (0)

    // prologue: stage tile 0
    stage_issue(0);
    stage_write(0);

#pragma unroll
    for (int k = 0; k < NK; ++k) {
        WLOAD(w0, 0); WLOAD(w1, 1); WLOAD(w2, 2);    // taps 0-2 fly over barrier
        if (k + 1 < NK) stage_issue(k + 1);          // next-tile loads fly over compute
        __syncthreads();                             // s_a[k&1] ready
        __builtin_amdgcn_s_setprio(1);
        WLOAD(w3, 3); CTAP(w0, 0);
        WLOAD(w0, 4); CTAP(w1, 1);
        WLOAD(w1, 5); CTAP(w2, 2);
        WLOAD(w2, 6); CTAP(w3, 3);
        WLOAD(w3, 7); CTAP(w0, 4);
        WLOAD(w0, 8); CTAP(w1, 5);
        CTAP(w2, 6);
        CTAP(w3, 7);
        CTAP(w0, 8);
        __builtin_amdgcn_s_setprio(0);
        if (k + 1 < NK) stage_write(k + 1);          // other buffer -> no fence here
    }
#undef WLOAD
#undef CTAP

    out += (size_t)zz * BB * Cout * HWS;
#pragma unroll
    for (int mt = 0; mt < 5; ++mt) {
#pragma unroll
        for (int nt = 0; nt < NW; ++nt) {
            int co = n0 + nt * 16 + r;
            int p = pix0 + mt * 16 + q * 4;
            *(f32x4*)&out[((size_t)b * Cout + co) * HWS + p] = acc[mt][nt];
        }
    }
}

// ---------------------------------------------------------------------------
// att = tanh(a0 + a1 + a2 + a3)  (4 stacked K-split partials, float4 loads)
// ---------------------------------------------------------------------------
__global__ void add_tanh4(const float* __restrict__ a0,
                          float* __restrict__ o, int n4) {
    int id = blockIdx.x * 256 + threadIdx.x;
    if (id >= n4) return;
    const f32x4* av = (const f32x4*)a0;
    f32x4 s = av[id] + av[id + (size_t)n4] + av[id + 2 * (size_t)n4]
            + av[id + 3 * (size_t)n4];
    f32x4 rr;
#pragma unroll
    for (int j = 0; j < 4; ++j) rr[j] = tanhf(s[j]);
    ((f32x4*)o)[id] = rr;
}

// ---------------------------------------------------------------------------
// K-split attention score: part[b][ch][p] = sum_{ca in chunk} sum_tap
//   att[b,ca,y+dy-1,x+dx-1] * Va[tap,ca]
// ---------------------------------------------------------------------------
__global__ __launch_bounds__(256) void att_e_part(
    const float* __restrict__ att, const float* __restrict__ Va,
    float* __restrict__ part)
{
    __shared__ float red[4][64];
    const int lane = threadIdx.x & 63, wv = threadIdx.x >> 6;
    const int p = blockIdx.x * 64 + lane;
    const int b = blockIdx.y, ch = blockIdx.z;
    const bool valid = (p < HWS);
    const int pc = valid ? p : 0;
    const int y = pc / WW, x = pc - (pc / WW) * WW;

    float acc = 0.f;
    if (valid) {
        const int ca0 = ch * 32 + wv * 8;
#pragma unroll
        for (int j = 0; j < 8; ++j) {
            const int ca = ca0 + j;
            const float* base = att + ((size_t)b * CC + ca) * HWS;
            const float* va = Va + ca;
#pragma unroll
            for (int dy = 0; dy < 3; ++dy) {
                int yy = y + dy - 1;
                if (yy < 0 || yy >= HH) continue;
#pragma unroll
                for (int dx = 0; dx < 3; ++dx) {
                    int xx = x + dx - 1;
                    if (xx < 0 || xx >= WW) continue;
                    acc = fmaf(base[yy * WW + xx], va[(dy * 3 + dx) * CC], acc);
                }
            }
        }
    }
    red[wv][lane] = acc;
    __syncthreads();
    if (wv == 0 && valid)
        part[((size_t)b * 8 + ch) * HWS + p] =
            red[0][lane] + red[1][lane] + red[2][lane] + red[3][lane];
}

// ---------------------------------------------------------------------------
// softmax over HW per batch, summing the 8 K-split partials first (in LDS)
// ---------------------------------------------------------------------------
__global__ __launch_bounds__(256) void softmax_kernel(
    const float* __restrict__ part, float* __restrict__ a)
{
    __shared__ float se[HWS];
    __shared__ float red[256];
    int b = blockIdx.x;
    int tid = threadIdx.x;

    for (int i = tid; i < HWS; i += 256) {
        float s = 0.f;
#pragma unroll
        for (int ch = 0; ch < 8; ++ch)
            s += part[((size_t)b * 8 + ch) * HWS + i];
        se[i] = s;
    }
    __syncthreads();

    float m = -1e30f;
    for (int i = tid; i < HWS; i += 256) m = fmaxf(m, se[i]);
    red[tid] = m;
    __syncthreads();
    for (int s = 128; s > 0; s >>= 1) {
        if (tid < s) red[tid] = fmaxf(red[tid], red[tid + s]);
        __syncthreads();
    }
    m = red[0];
    __syncthreads();

    float sum = 0.f;
    for (int i = tid; i < HWS; i += 256) {
        float v = expf(se[i] - m);
        se[i] = v;
        sum += v;
    }
    red[tid] = sum;
    __syncthreads();
    for (int s = 128; s > 0; s >>= 1) {
        if (tid < s) red[tid] += red[tid + s];
        __syncthreads();
    }
    float inv = 1.f / red[0];
    for (int i = tid; i < HWS; i += 256)
        a[(size_t)b * HWS + i] = se[i] * inv;
}

// ---------------------------------------------------------------------------
// LSTM gate update; emits h16 (blocked f16) always, h f32 only on last step.
// ---------------------------------------------------------------------------
__global__ void gate_update(const float* __restrict__ g0, const float* __restrict__ g1,
                            float* __restrict__ c, _Float16* __restrict__ h16,
                            float* __restrict__ h32) {
    int id = blockIdx.x * 256 + threadIdx.x;
    if (id >= BB * NCG * HWS) return;
    int p = id % HWS;
    int cig = (id / HWS) % NCG;
    int b = id / (HWS * NCG);
    const int ci0 = cig * 8;
    half8 hv;
#pragma unroll
    for (int j = 0; j < 8; ++j) {
        size_t base = ((size_t)b * 4 * CC + ci0 + j) * HWS + p;
        float gi = g0[base] + g1[base];
        float gf = g0[base + (size_t)CHW] + g1[base + (size_t)CHW];
        float gc = g0[base + 2 * (size_t)CHW] + g1[base + 2 * (size_t)CHW];
        float go = g0[base + 3 * (size_t)CHW] + g1[base + 3 * (size_t)CHW];
        float i_ = 1.f / (1.f + expf(-gi));
        float f_ = 1.f / (1.f + expf(-gf));
        float o_ = 1.f / (1.f + expf(-go));
        size_t cix = ((size_t)b * CC + ci0 + j) * HWS + p;
        float cn = f_ * c[cix] + i_ * tanhf(gc);
        c[cix] = cn;
        float hn = o_ * tanhf(cn);
        hv[j] = (_Float16)hn;
        if (h32) h32[cix] = hn;
    }
    *(half8*)&h16[(size_t)id * 8] = hv;
}

// ---------------------------------------------------------------------------
extern "C" void kernel_launch(void* const* d_in, const int* in_sizes, int n_in,
                              void* d_out, int out_size, void* d_ws, size_t ws_size,
                              hipStream_t stream) {
    const float* x   = (const float*)d_in[0];
    const float* Wa  = (const float*)d_in[1];
    const float* ba  = (const float*)d_in[2];
    const float* Ua  = (const float*)d_in[3];
    const float* bua = (const float*)d_in[4];
    const float* Va  = (const float*)d_in[5];
    const float* Wx  = (const float*)d_in[6];
    const float* bx  = (const float*)d_in[7];
    const float* Uh  = (const float*)d_in[8];
    const float* bh  = (const float*)d_in[9];
    float* out = (float*)d_out;

    char* wsb = (char*)d_ws;
    const size_t NCHW = (size_t)BB * CHW;
    _Float16* wtg  = (_Float16*)wsb;              wsb += (size_t)4608 * 1024 * 2;
    _Float16* wta  = (_Float16*)wsb;              wsb += (size_t)4608 * 256 * 2;
    _Float16* x16  = (_Float16*)wsb;              wsb += (size_t)BB * TT * PXS * 2;
    _Float16* h16  = (_Float16*)wsb;              wsb += (size_t)BB * PXS * 2;
    _Float16* xt16 = (_Float16*)wsb;              wsb += (size_t)BB * PXS * 2;
    float* cb   = (float*)wsb;                    wsb += NCHW * 4;
    float* g01  = (float*)wsb;                    wsb += 8 * NCHW * 4;   // z-stacked
    float* att  = (float*)wsb;                    wsb += NCHW * 4;
    float* part = (float*)wsb;                    wsb += (size_t)BB * 8 * HWS * 4;
    float* a    = (float*)wsb;
    // att01 (4 z-stacked partials, Cout=256) aliases g01 (disjoint lifetime)
    float* att01 = g01;

    pack_weights<<<dim3((4608 * 1024 + 255) / 256), dim3(256), 0, stream>>>(
        Wx, Uh, wtg, 1024);
    pack_weights<<<dim3((4608 * 256 + 255) / 256), dim3(256), 0, stream>>>(
        Wa, Ua, wta, 256);
    pack_x16<<<dim3((BB * TT * NCG * HWS + 255) / 256), dim3(256), 0, stream>>>(
        x, x16);

    const int nblk = BB * NCG * HWS;              // 153600
    init_hc<<<dim3((nblk + 255) / 256), dim3(256), 0, stream>>>(x, h16, cb);

    const int n4 = (int)(NCHW / 4);

    for (int t = 0; t < TT; ++t) {
        // attention partials: NW=2, 8 slices (2 cout-chunks x 2 src x 2 ci-halves),
        // 480 blocks, 1 slice per XCD. z=0 carries bias.
        conv_mfma<2, 2, 2, 4><<<dim3(480), dim3(256), 0, stream>>>(
            h16, (long)PXS, x16 + (size_t)t * PXS, (long)TT * PXS,
            wta, ba, bua, att01, 256);
        add_tanh4<<<dim3((n4 + 255) / 256), dim3(256), 0, stream>>>(
            att01, att, n4);

        att_e_part<<<dim3(19, BB, 8), dim3(256), 0, stream>>>(att, Va, part);
        softmax_kernel<<<dim3(BB), dim3(256), 0, stream>>>(part, a);

        // x_tilde in f16 blocked
        xtilde_kernel<<<dim3((nblk + 255) / 256), dim3(256), 0, stream>>>(
            x + (size_t)t * CHW, a, xt16);

        // gates: NW=4, 8 slices (4 cout-chunks x 2 src), 480 blocks,
        // 1 slice per XCD (XCD 0-3: xt16/Wx, XCD 4-7: h16/Uh).
        conv_mfma<4, 1, 4, 2><<<dim3(480), dim3(256), 0, stream>>>(
            xt16, (long)PXS, h16, (long)PXS, wtg, bx, bh, g01, 1024);

        gate_update<<<dim3((nblk + 255) / 256), dim3(256), 0, stream>>>(
            g01, g01 + 4 * NCHW, cb, h16, (t == TT - 1) ? out : nullptr);
    }
}